// Round 1
// baseline (1700.540 us; speedup 1.0000x reference)
//
#include <hip/hip_runtime.h>
#include <math.h>

#define B_ 4
#define N_ 256
#define D_ 128
#define H_ 256
#define K_ 8

// ---------------------------------------------------------------------------
// Prep kernel: one block per (b,n), 256 threads (thread = h).
//  - Ag[b,n,h]  = s[b,n,:] @ Wg1[0:128,h]   + bg1[h]   (the "i" term, bias folded)
//  - BgT[b,h,n] = s[b,n,:] @ Wg1[128:256,h]            (the "j" term, transposed)
//  - same for the attention net (Aa, BaT)
//  - sT[b,d,n]  = s[b,n,d]                              (for coalesced row loads)
//  - WgcT[h,d]  = Wg1[256+d,h], WacT[h,d] = Wa1[256+d,h] (wave-uniform weight reads)
// ---------------------------------------------------------------------------
__global__ __launch_bounds__(256) void prep_kernel(
    const float* __restrict__ s,
    const float* __restrict__ Wg1, const float* __restrict__ bg1,
    const float* __restrict__ Wa1, const float* __restrict__ ba1,
    float* __restrict__ sT,
    float* __restrict__ Ag, float* __restrict__ BgT,
    float* __restrict__ Aa, float* __restrict__ BaT,
    float* __restrict__ WgcT, float* __restrict__ WacT) {
  const int b = blockIdx.x >> 8;
  const int n = blockIdx.x & 255;
  const int h = threadIdx.x;

  __shared__ float sh[D_];
  if (h < D_) sh[h] = s[(b * N_ + n) * D_ + h];
  __syncthreads();

  float ag = bg1[h], bg = 0.f, aa = ba1[h], ba = 0.f;
#pragma unroll 8
  for (int d = 0; d < D_; d++) {
    const float sd = sh[d];
    ag = fmaf(sd, Wg1[d * H_ + h], ag);              // coalesced over h
    bg = fmaf(sd, Wg1[(D_ + d) * H_ + h], bg);
    aa = fmaf(sd, Wa1[d * H_ + h], aa);
    ba = fmaf(sd, Wa1[(D_ + d) * H_ + h], ba);
  }
  Ag[(b * N_ + n) * H_ + h] = ag;
  BgT[(b * H_ + h) * N_ + n] = bg;
  Aa[(b * N_ + n) * H_ + h] = aa;
  BaT[(b * H_ + h) * N_ + n] = ba;

  if (h < D_) sT[(b * D_ + h) * N_ + n] = sh[h];

  if (blockIdx.x < D_) {  // blocks 0..127 (b==0) also transpose the W1c slabs
    const int d = blockIdx.x;
    WgcT[h * D_ + d] = Wg1[(2 * D_ + d) * H_ + h];
    WacT[h * D_ + d] = Wa1[(2 * D_ + d) * H_ + h];
  }
}

__device__ inline void arg_better(float v2, int i2, float& v, int& idx) {
  if (v2 > v || (v2 == v && i2 < idx)) { v = v2; idx = i2; }
}

// ---------------------------------------------------------------------------
// Main kernel: one block per (b,i), 256 threads (thread = j).
// Computes both MLP scores for all j, top-8 select, softmax, gate/att/ctx.
// ---------------------------------------------------------------------------
__global__ __launch_bounds__(256, 2) void score_kernel(
    const float* __restrict__ s,
    const float* __restrict__ sT,
    const float* __restrict__ Ag, const float* __restrict__ BgT,
    const float* __restrict__ Aa, const float* __restrict__ BaT,
    const float* __restrict__ WgcT, const float* __restrict__ WacT,
    const float* __restrict__ Wg2, const float* __restrict__ bg2p,
    const float* __restrict__ Wa2, const float* __restrict__ ba2p,
    float* __restrict__ out) {
  const int b = blockIdx.x >> 8;
  const int i = blockIdx.x & 255;
  const int j = threadIdx.x;

  __shared__ float si[D_];
  __shared__ float scg_sh[N_];
  __shared__ float att_sh[N_];
  __shared__ float red_v[4];
  __shared__ int red_i[4];
  __shared__ int sel_list[K_];

  if (j < D_) si[j] = s[(b * N_ + i) * D_ + j];
  __syncthreads();

  // p[d] = s[b,i,d] * s[b,j,d]   (sT read is coalesced across j)
  float p[D_];
#pragma unroll
  for (int d = 0; d < D_; d++) p[d] = si[d] * sT[(b * D_ + d) * N_ + j];

  const float* __restrict__ Agp = Ag + (b * N_ + i) * H_;
  const float* __restrict__ Aap = Aa + (b * N_ + i) * H_;
  const float* __restrict__ BgTp = BgT + b * H_ * N_ + j;
  const float* __restrict__ BaTp = BaT + b * H_ * N_ + j;

  float scg = bg2p[0];
  float sca = ba2p[0];

  for (int h = 0; h < H_; h += 4) {
    const float* __restrict__ wg = WgcT + h * D_;   // wave-uniform addresses
    const float* __restrict__ wa = WacT + h * D_;
    float hg0 = 0.f, hg1 = 0.f, hg2 = 0.f, hg3 = 0.f;
    float ha0 = 0.f, ha1 = 0.f, ha2 = 0.f, ha3 = 0.f;
#pragma unroll 4
    for (int d = 0; d < D_; d++) {
      const float pd = p[d];
      hg0 = fmaf(pd, wg[d], hg0);
      hg1 = fmaf(pd, wg[D_ + d], hg1);
      hg2 = fmaf(pd, wg[2 * D_ + d], hg2);
      hg3 = fmaf(pd, wg[3 * D_ + d], hg3);
      ha0 = fmaf(pd, wa[d], ha0);
      ha1 = fmaf(pd, wa[D_ + d], ha1);
      ha2 = fmaf(pd, wa[2 * D_ + d], ha2);
      ha3 = fmaf(pd, wa[3 * D_ + d], ha3);
    }
    hg0 += Agp[h + 0] + BgTp[(h + 0) * N_];
    hg1 += Agp[h + 1] + BgTp[(h + 1) * N_];
    hg2 += Agp[h + 2] + BgTp[(h + 2) * N_];
    hg3 += Agp[h + 3] + BgTp[(h + 3) * N_];
    ha0 += Aap[h + 0] + BaTp[(h + 0) * N_];
    ha1 += Aap[h + 1] + BaTp[(h + 1) * N_];
    ha2 += Aap[h + 2] + BaTp[(h + 2) * N_];
    ha3 += Aap[h + 3] + BaTp[(h + 3) * N_];
    scg = fmaf(fmaxf(hg0, 0.f), Wg2[h + 0], scg);
    scg = fmaf(fmaxf(hg1, 0.f), Wg2[h + 1], scg);
    scg = fmaf(fmaxf(hg2, 0.f), Wg2[h + 2], scg);
    scg = fmaf(fmaxf(hg3, 0.f), Wg2[h + 3], scg);
    sca = fmaf(fmaxf(ha0, 0.f), Wa2[h + 0], sca);
    sca = fmaf(fmaxf(ha1, 0.f), Wa2[h + 1], sca);
    sca = fmaf(fmaxf(ha2, 0.f), Wa2[h + 2], sca);
    sca = fmaf(fmaxf(ha3, 0.f), Wa2[h + 3], sca);
  }

  scg_sh[j] = scg;
  __syncthreads();

  // ---- top-8 over j: value desc, index asc (matches jax.lax.top_k set) ----
  for (int k = 0; k < K_; k++) {
    float v = scg_sh[j];
    int idx = j;
#pragma unroll
    for (int off = 32; off > 0; off >>= 1) {
      const float vo = __shfl_down(v, off, 64);
      const int io = __shfl_down(idx, off, 64);
      arg_better(vo, io, v, idx);
    }
    if ((j & 63) == 0) { red_v[j >> 6] = v; red_i[j >> 6] = idx; }
    __syncthreads();
    if (j == 0) {
      float bv = red_v[0];
      int bi = red_i[0];
      for (int w = 1; w < 4; w++) arg_better(red_v[w], red_i[w], bv, bi);
      sel_list[k] = bi;
      scg_sh[bi] = -INFINITY;   // remove from next round
    }
    __syncthreads();
  }

  bool selj = false;
#pragma unroll
  for (int k = 0; k < K_; k++) selj = selj || (sel_list[k] == j);

  // ---- softmax over the selected attention logits ----
  att_sh[j] = sca;
  __syncthreads();
  if (j == 0) {
    float m = -INFINITY;
    for (int k = 0; k < K_; k++) m = fmaxf(m, att_sh[sel_list[k]]);
    float ssum = 0.f;
    for (int k = 0; k < K_; k++) ssum += expf(att_sh[sel_list[k]] - m);
    red_v[0] = m;
    red_v[1] = ssum;
  }
  __syncthreads();
  const float att = selj ? expf(sca - red_v[0]) / red_v[1] : 0.f;

  // ---- outputs ----
  float* __restrict__ ctx_out = out;                                   // [B,N,D]
  float* __restrict__ gate_out = out + B_ * N_ * D_;                   // [B,N,N]
  float* __restrict__ att_out = out + B_ * N_ * D_ + B_ * N_ * N_;     // [B,N,N]

  const int row = (b * N_ + i) * N_;
  gate_out[row + j] = selj ? 1.f : 0.f;
  att_out[row + j] = att;

  __syncthreads();
  att_sh[j] = att;   // reuse as att row for ctx gather
  __syncthreads();

  if (j < D_) {
    float acc = 0.f;
#pragma unroll
    for (int k = 0; k < K_; k++) {
      const int jj = sel_list[k];
      acc = fmaf(att_sh[jj], s[(b * N_ + jj) * D_ + j], acc);
    }
    ctx_out[(b * N_ + i) * D_ + j] = acc;
  }
}

extern "C" void kernel_launch(void* const* d_in, const int* in_sizes, int n_in,
                              void* d_out, int out_size, void* d_ws, size_t ws_size,
                              hipStream_t stream) {
  const float* s   = (const float*)d_in[0];
  const float* Wg1 = (const float*)d_in[1];
  const float* bg1 = (const float*)d_in[2];
  const float* Wg2 = (const float*)d_in[3];
  const float* bg2 = (const float*)d_in[4];
  const float* Wa1 = (const float*)d_in[5];
  const float* ba1 = (const float*)d_in[6];
  const float* Wa2 = (const float*)d_in[7];
  const float* ba2 = (const float*)d_in[8];
  float* out = (float*)d_out;

  float* ws = (float*)d_ws;
  float* sT   = ws;                       // B*D*N   = 131072
  float* Ag   = sT + B_ * D_ * N_;        // B*N*H   = 262144
  float* BgT  = Ag + B_ * N_ * H_;        // B*H*N   = 262144
  float* Aa   = BgT + B_ * H_ * N_;       // 262144
  float* BaT  = Aa + B_ * N_ * H_;        // 262144
  float* WgcT = BaT + B_ * H_ * N_;       // H*D     = 32768
  float* WacT = WgcT + H_ * D_;           // 32768

  prep_kernel<<<dim3(B_ * N_), dim3(256), 0, stream>>>(
      s, Wg1, bg1, Wa1, ba1, sT, Ag, BgT, Aa, BaT, WgcT, WacT);

  score_kernel<<<dim3(B_ * N_), dim3(256), 0, stream>>>(
      s, sT, Ag, BgT, Aa, BaT, WgcT, WacT, Wg2, bg2, Wa2, ba2, out);
}

// Round 2
// 893.149 us; speedup vs baseline: 1.9040x; 1.9040x over previous
//
#include <hip/hip_runtime.h>
#include <math.h>

#define B_ 4
#define N_ 256
#define D_ 128
#define H_ 256
#define K_ 8

// ---------------------------------------------------------------------------
// Prep kernel: one block per (b,n), 256 threads (thread = h).
//  - Ag[b,n,h]  = s[b,n,:] @ Wg1[0:128,h]   + bg1[h]   (the "i" term, bias folded)
//  - BgT[b,h,n] = s[b,n,:] @ Wg1[128:256,h]            (the "j" term, transposed)
//  - same for the attention net (Aa, BaT)
//  - sT[b,d,n]  = s[b,n,d]                              (for coalesced row loads)
//  - WgcT[h,d]  = Wg1[256+d,h], WacT[h,d] = Wa1[256+d,h] (wave-uniform weight reads)
// ---------------------------------------------------------------------------
__global__ __launch_bounds__(256) void prep_kernel(
    const float* __restrict__ s,
    const float* __restrict__ Wg1, const float* __restrict__ bg1,
    const float* __restrict__ Wa1, const float* __restrict__ ba1,
    float* __restrict__ sT,
    float* __restrict__ Ag, float* __restrict__ BgT,
    float* __restrict__ Aa, float* __restrict__ BaT,
    float* __restrict__ WgcT, float* __restrict__ WacT) {
  const int b = blockIdx.x >> 8;
  const int n = blockIdx.x & 255;
  const int h = threadIdx.x;

  __shared__ float sh[D_];
  if (h < D_) sh[h] = s[(b * N_ + n) * D_ + h];
  __syncthreads();

  float ag = bg1[h], bg = 0.f, aa = ba1[h], ba = 0.f;
#pragma unroll 8
  for (int d = 0; d < D_; d++) {
    const float sd = sh[d];
    ag = fmaf(sd, Wg1[d * H_ + h], ag);              // coalesced over h
    bg = fmaf(sd, Wg1[(D_ + d) * H_ + h], bg);
    aa = fmaf(sd, Wa1[d * H_ + h], aa);
    ba = fmaf(sd, Wa1[(D_ + d) * H_ + h], ba);
  }
  Ag[(b * N_ + n) * H_ + h] = ag;
  BgT[(b * H_ + h) * N_ + n] = bg;
  Aa[(b * N_ + n) * H_ + h] = aa;
  BaT[(b * H_ + h) * N_ + n] = ba;

  if (h < D_) sT[(b * D_ + h) * N_ + n] = sh[h];

  if (blockIdx.x < D_) {  // blocks 0..127 (b==0) also transpose the W1c slabs
    const int d = blockIdx.x;
    WgcT[h * D_ + d] = Wg1[(2 * D_ + d) * H_ + h];
    WacT[h * D_ + d] = Wa1[(2 * D_ + d) * H_ + h];
  }
}

__device__ inline void arg_better(float v2, int i2, float& v, int& idx) {
  if (v2 > v || (v2 == v && i2 < idx)) { v = v2; idx = i2; }
}

// ---------------------------------------------------------------------------
// Main kernel: one block per (b,i), 256 threads (thread = j).
// p[] MUST stay in VGPRs: every loop touching p is FULLY unrolled so all
// indices are compile-time constants (R1's partial unroll demoted p to
// scratch -> 4 GB of scratch traffic, VGPR_Count=36).
// ---------------------------------------------------------------------------
__global__ __launch_bounds__(256, 2) void score_kernel(
    const float* __restrict__ s,
    const float* __restrict__ sT,
    const float* __restrict__ Ag, const float* __restrict__ BgT,
    const float* __restrict__ Aa, const float* __restrict__ BaT,
    const float* __restrict__ WgcT, const float* __restrict__ WacT,
    const float* __restrict__ Wg2, const float* __restrict__ bg2p,
    const float* __restrict__ Wa2, const float* __restrict__ ba2p,
    float* __restrict__ out) {
  const int b = blockIdx.x >> 8;
  const int i = blockIdx.x & 255;
  const int j = threadIdx.x;

  __shared__ float si[D_];
  __shared__ float scg_sh[N_];
  __shared__ float att_sh[N_];
  __shared__ float red_v[4];
  __shared__ int red_i[4];
  __shared__ int sel_list[K_];

  if (j < D_) si[j] = s[(b * N_ + i) * D_ + j];
  __syncthreads();

  // p[d] = s[b,i,d] * s[b,j,d]   (sT read is coalesced across j)
  float p[D_];
#pragma unroll
  for (int d = 0; d < D_; d++) p[d] = si[d] * sT[(b * D_ + d) * N_ + j];

  const float* __restrict__ Agp = Ag + (b * N_ + i) * H_;
  const float* __restrict__ Aap = Aa + (b * N_ + i) * H_;
  const float* __restrict__ BgTp = BgT + b * H_ * N_ + j;
  const float* __restrict__ BaTp = BaT + b * H_ * N_ + j;

  float scg = bg2p[0];
  float sca = ba2p[0];

#pragma unroll 1
  for (int h = 0; h < H_; h += 2) {
    const float* __restrict__ wg = WgcT + h * D_;   // uniform -> s_load
    const float* __restrict__ wa = WacT + h * D_;
    float hg0 = 0.f, hg1 = 0.f;
    float ha0 = 0.f, ha1 = 0.f;
#pragma unroll
    for (int d = 0; d < D_; d++) {                  // FULL unroll: p[d] const idx
      const float pd = p[d];
      hg0 = fmaf(pd, wg[d], hg0);
      hg1 = fmaf(pd, wg[D_ + d], hg1);
      ha0 = fmaf(pd, wa[d], ha0);
      ha1 = fmaf(pd, wa[D_ + d], ha1);
    }
    hg0 += Agp[h + 0] + BgTp[(h + 0) * N_];
    hg1 += Agp[h + 1] + BgTp[(h + 1) * N_];
    ha0 += Aap[h + 0] + BaTp[(h + 0) * N_];
    ha1 += Aap[h + 1] + BaTp[(h + 1) * N_];
    scg = fmaf(fmaxf(hg0, 0.f), Wg2[h + 0], scg);
    scg = fmaf(fmaxf(hg1, 0.f), Wg2[h + 1], scg);
    sca = fmaf(fmaxf(ha0, 0.f), Wa2[h + 0], sca);
    sca = fmaf(fmaxf(ha1, 0.f), Wa2[h + 1], sca);
  }

  scg_sh[j] = scg;
  __syncthreads();

  // ---- top-8 over j: value desc, index asc (matches jax.lax.top_k set) ----
  for (int k = 0; k < K_; k++) {
    float v = scg_sh[j];
    int idx = j;
#pragma unroll
    for (int off = 32; off > 0; off >>= 1) {
      const float vo = __shfl_down(v, off, 64);
      const int io = __shfl_down(idx, off, 64);
      arg_better(vo, io, v, idx);
    }
    if ((j & 63) == 0) { red_v[j >> 6] = v; red_i[j >> 6] = idx; }
    __syncthreads();
    if (j == 0) {
      float bv = red_v[0];
      int bi = red_i[0];
      for (int w = 1; w < 4; w++) arg_better(red_v[w], red_i[w], bv, bi);
      sel_list[k] = bi;
      scg_sh[bi] = -INFINITY;   // remove from next round
    }
    __syncthreads();
  }

  bool selj = false;
#pragma unroll
  for (int k = 0; k < K_; k++) selj = selj || (sel_list[k] == j);

  // ---- softmax over the selected attention logits ----
  att_sh[j] = sca;
  __syncthreads();
  if (j == 0) {
    float m = -INFINITY;
    for (int k = 0; k < K_; k++) m = fmaxf(m, att_sh[sel_list[k]]);
    float ssum = 0.f;
    for (int k = 0; k < K_; k++) ssum += expf(att_sh[sel_list[k]] - m);
    red_v[0] = m;
    red_v[1] = ssum;
  }
  __syncthreads();
  const float att = selj ? expf(sca - red_v[0]) / red_v[1] : 0.f;

  // ---- outputs ----
  float* __restrict__ ctx_out = out;                                   // [B,N,D]
  float* __restrict__ gate_out = out + B_ * N_ * D_;                   // [B,N,N]
  float* __restrict__ att_out = out + B_ * N_ * D_ + B_ * N_ * N_;     // [B,N,N]

  const int row = (b * N_ + i) * N_;
  gate_out[row + j] = selj ? 1.f : 0.f;
  att_out[row + j] = att;

  __syncthreads();
  att_sh[j] = att;   // reuse as att row for ctx gather
  __syncthreads();

  if (j < D_) {
    float acc = 0.f;
#pragma unroll
    for (int k = 0; k < K_; k++) {
      const int jj = sel_list[k];
      acc = fmaf(att_sh[jj], s[(b * N_ + jj) * D_ + j], acc);
    }
    ctx_out[(b * N_ + i) * D_ + j] = acc;
  }
}

extern "C" void kernel_launch(void* const* d_in, const int* in_sizes, int n_in,
                              void* d_out, int out_size, void* d_ws, size_t ws_size,
                              hipStream_t stream) {
  const float* s   = (const float*)d_in[0];
  const float* Wg1 = (const float*)d_in[1];
  const float* bg1 = (const float*)d_in[2];
  const float* Wg2 = (const float*)d_in[3];
  const float* bg2 = (const float*)d_in[4];
  const float* Wa1 = (const float*)d_in[5];
  const float* ba1 = (const float*)d_in[6];
  const float* Wa2 = (const float*)d_in[7];
  const float* ba2 = (const float*)d_in[8];
  float* out = (float*)d_out;

  float* ws = (float*)d_ws;
  float* sT   = ws;                       // B*D*N   = 131072
  float* Ag   = sT + B_ * D_ * N_;        // B*N*H   = 262144
  float* BgT  = Ag + B_ * N_ * H_;        // B*H*N   = 262144
  float* Aa   = BgT + B_ * H_ * N_;       // 262144
  float* BaT  = Aa + B_ * N_ * H_;        // 262144
  float* WgcT = BaT + B_ * H_ * N_;       // H*D     = 32768
  float* WacT = WgcT + H_ * D_;           // 32768

  prep_kernel<<<dim3(B_ * N_), dim3(256), 0, stream>>>(
      s, Wg1, bg1, Wa1, ba1, sT, Ag, BgT, Aa, BaT, WgcT, WacT);

  score_kernel<<<dim3(B_ * N_), dim3(256), 0, stream>>>(
      s, sT, Ag, BgT, Aa, BaT, WgcT, WacT, Wg2, bg2, Wa2, ba2, out);
}